// Round 2
// baseline (294.577 us; speedup 1.0000x reference)
//
#include <hip/hip_runtime.h>
#include <cmath>

#define NN 64
#define CC 256
#define TT 64
#define VV 25
#define OO 512     // 2*out_planes
#define GG 8
#define NV (NN*VV)   // 1600 elements per channel for qkv/so BN
#define STK 625      // V*V

// ---------------- kernel 1: y[n,c,v] = mean_t x[n,c,t,v] ----------------
__global__ __launch_bounds__(256) void k_mean(const float* __restrict__ x,
                                              float* __restrict__ y) {
    __shared__ float tile[TT * VV];   // 1600 floats
    __shared__ float part[8 * VV];
    int b = blockIdx.x;               // n*CC + c
    int t = threadIdx.x;
    const float4* x4 = (const float4*)(x + (size_t)b * (TT * VV));
    float4* t4 = (float4*)tile;
    for (int i = t; i < (TT * VV) / 4; i += 256) t4[i] = x4[i];
    __syncthreads();
    if (t < 200) {                    // stage 1: 8 partials per v
        int v = t % VV, s = t / VV;   // s in 0..7
        float a = 0.f;
        #pragma unroll
        for (int k = 0; k < 8; ++k) a += tile[(s * 8 + k) * VV + v];
        part[s * VV + v] = a;
    }
    __syncthreads();
    if (t < VV) {
        float a = 0.f;
        #pragma unroll
        for (int s = 0; s < 8; ++s) a += part[s * VV + t];
        y[(size_t)b * VV + t] = a * (1.0f / TT);
    }
}

// ---------------- kernel 2: qkv = w @ y, fused per-channel (sum,sumsq) atomics ----------------
__global__ __launch_bounds__(256) void k_gemm(const float* __restrict__ y,
                                              const float* __restrict__ w,
                                              float* __restrict__ qkv,
                                              float* __restrict__ qstat) {
    __shared__ float ys[CC * VV];     // 6400 floats, reused as scratch later
    int n = blockIdx.x >> 3, oc = blockIdx.x & 7;
    int t = threadIdx.x;
    const float* yp = y + (size_t)n * CC * VV;
    for (int i = t; i < CC * VV; i += 256) ys[i] = yp[i];
    __syncthreads();
    int v = t % VV, o0 = t / VV;      // valid for t<200; o0 in 0..7
    int obase = oc * 64 + o0;
    float acc[8] = {0, 0, 0, 0, 0, 0, 0, 0};
    if (t < 200) {
        for (int c = 0; c < CC; c += 4) {
            float y0 = ys[c * VV + v], y1 = ys[(c + 1) * VV + v];
            float y2 = ys[(c + 2) * VV + v], y3 = ys[(c + 3) * VV + v];
            #pragma unroll
            for (int u = 0; u < 8; ++u) {
                const float4 w4 = *(const float4*)&w[(size_t)(obase + u * 8) * CC + c];
                acc[u] += y0 * w4.x + y1 * w4.y + y2 * w4.z + y3 * w4.w;
            }
        }
        #pragma unroll
        for (int u = 0; u < 8; ++u)
            qkv[((size_t)n * OO + obase + u * 8) * VV + v] = acc[u];
    }
    __syncthreads();                  // done reading ys -> reuse as scratch
    if (t < 200) {
        #pragma unroll
        for (int u = 0; u < 8; ++u) ys[(o0 + 8 * u) * VV + v] = acc[u];
    }
    __syncthreads();
    if (t < 64) {
        float s = 0.f, s2 = 0.f;
        #pragma unroll
        for (int k = 0; k < VV; ++k) { float w0 = ys[t * VV + k]; s += w0; s2 += w0 * w0; }
        int ch = oc * 64 + t;
        atomicAdd(&qstat[2 * ch], s);
        atomicAdd(&qstat[2 * ch + 1], s2);
    }
}

// ---------------- kernel 3: qkv-BN -> qk/qr/kr scores, fused sim-stat atomics ----------------
__global__ __launch_bounds__(256) void k_scores(const float* __restrict__ qkv,
                                                const float* __restrict__ rel,
                                                const float* __restrict__ qstat,
                                                const float* __restrict__ gq,
                                                const float* __restrict__ bq,
                                                float* __restrict__ stk,
                                                float* __restrict__ sstat) {
    int n = blockIdx.x >> 3, gidx = blockIdx.x & 7;
    __shared__ float qs[16][VV], ks[16][VV], rs[32][49];
    __shared__ float qscl[32], qshl[32];
    __shared__ float red0[256], red1[256], red2[256];
    int t = threadIdx.x;
    if (t < 32) {
        int o = gidx * 64 + t;
        float s = qstat[2 * o], s2 = qstat[2 * o + 1];
        float m = s * (1.0f / NV), var = s2 * (1.0f / NV) - m * m;
        float sc = gq[o] * rsqrtf(var + 1e-5f);
        qscl[t] = sc; qshl[t] = bq[o] - m * sc;
    }
    __syncthreads();
    for (int i = t; i < 32 * VV; i += 256) {
        int c = i / VV, v = i - c * VV;
        int o = gidx * 64 + c;
        float val = qkv[((size_t)n * OO + o) * VV + v] * qscl[c] + qshl[c];
        if (c < 16) qs[c][v] = val; else ks[c - 16][v] = val;
    }
    for (int i = t; i < 32 * 49; i += 256) rs[i / 49][i % 49] = rel[i];
    __syncthreads();
    float sqk = 0.f, sqr = 0.f, skr = 0.f, sqk2 = 0.f, sqr2 = 0.f, skr2 = 0.f;
    for (int ij = t; ij < STK; ij += 256) {
        int i = ij / VV, j = ij - (ij / VV) * VV;
        float aqk = 0.f, aqr = 0.f, akr = 0.f;
        #pragma unroll
        for (int c = 0; c < 16; ++c) {
            float qv = qs[c][i], kv = ks[c][j];
            aqk += qv * kv;
            aqr += qv * rs[c][i - j + 24];
            akr += kv * rs[16 + c][j - i + 24];
        }
        size_t base = (size_t)n * 24;
        stk[(base + gidx) * STK + ij]      = aqk;
        stk[(base + 8 + gidx) * STK + ij]  = aqr;
        stk[(base + 16 + gidx) * STK + ij] = akr;
        sqk += aqk; sqk2 += aqk * aqk;
        sqr += aqr; sqr2 += aqr * aqr;
        skr += akr; skr2 += akr * akr;
    }
    red0[t] = sqk; red1[t] = sqr; red2[t] = skr;
    __syncthreads();
    for (int off = 128; off > 0; off >>= 1) {
        if (t < off) { red0[t] += red0[t + off]; red1[t] += red1[t + off]; red2[t] += red2[t + off]; }
        __syncthreads();
    }
    if (t == 0) {
        atomicAdd(&sstat[2 * gidx], red0[0]);
        atomicAdd(&sstat[2 * (8 + gidx)], red1[0]);
        atomicAdd(&sstat[2 * (16 + gidx)], red2[0]);
    }
    __syncthreads();
    red0[t] = sqk2; red1[t] = sqr2; red2[t] = skr2;
    __syncthreads();
    for (int off = 128; off > 0; off >>= 1) {
        if (t < off) { red0[t] += red0[t + off]; red1[t] += red1[t + off]; red2[t] += red2[t + off]; }
        __syncthreads();
    }
    if (t == 0) {
        atomicAdd(&sstat[2 * gidx + 1], red0[0]);
        atomicAdd(&sstat[2 * (8 + gidx) + 1], red1[0]);
        atomicAdd(&sstat[2 * (16 + gidx) + 1], red2[0]);
    }
}

// ---------------- kernel 4: sim-BN+sum -> softmax -> sv/sve, fused so-stat atomics ----------------
__global__ __launch_bounds__(256) void k_attnout(const float* __restrict__ stk,
                                                 const float* __restrict__ qkv,
                                                 const float* __restrict__ rel,
                                                 const float* __restrict__ qstat,
                                                 const float* __restrict__ gq,
                                                 const float* __restrict__ bq,
                                                 const float* __restrict__ sstat,
                                                 const float* __restrict__ gs,
                                                 const float* __restrict__ bs,
                                                 float* __restrict__ so,
                                                 float* __restrict__ ostat) {
    int n = blockIdx.x >> 3, gidx = blockIdx.x & 7;
    __shared__ float S[STK];
    __shared__ float vs[32][VV];
    __shared__ float rs[32][49];
    __shared__ float scratch[64 * VV];
    __shared__ float sscl[3], sshl[3], vscl[32], vshl[32];
    int t = threadIdx.x;
    if (t < 3) {
        int ch = 8 * t + gidx;
        float s = sstat[2 * ch], s2 = sstat[2 * ch + 1];
        const float inv = 1.0f / 40000.0f;
        float m = s * inv, var = s2 * inv - m * m;
        float sc = gs[ch] * rsqrtf(var + 1e-5f);
        sscl[t] = sc; sshl[t] = bs[ch] - m * sc;
    }
    if (t >= 32 && t < 64) {
        int c = t - 32;
        int o = gidx * 64 + 32 + c;
        float s = qstat[2 * o], s2 = qstat[2 * o + 1];
        float m = s * (1.0f / NV), var = s2 * (1.0f / NV) - m * m;
        float sc = gq[o] * rsqrtf(var + 1e-5f);
        vscl[c] = sc; vshl[c] = bq[o] - m * sc;
    }
    __syncthreads();
    const size_t sb = (size_t)n * 24 * STK;
    for (int ij = t; ij < STK; ij += 256) {
        float a = stk[sb + (size_t)gidx * STK + ij] * sscl[0] + sshl[0];
        a += stk[sb + (size_t)(8 + gidx) * STK + ij] * sscl[1] + sshl[1];
        a += stk[sb + (size_t)(16 + gidx) * STK + ij] * sscl[2] + sshl[2];
        S[ij] = a;
    }
    for (int i = t; i < 32 * VV; i += 256) {
        int c = i / VV, v = i - (i / VV) * VV;
        int o = gidx * 64 + 32 + c;
        vs[c][v] = qkv[((size_t)n * OO + o) * VV + v] * vscl[c] + vshl[c];
    }
    for (int i = t; i < 32 * 49; i += 256) rs[i / 49][i % 49] = rel[32 * 49 + i];
    __syncthreads();
    if (t < VV) {
        int i = t;
        float m = -1e30f;
        #pragma unroll
        for (int j = 0; j < VV; ++j) m = fmaxf(m, S[i * VV + j]);
        float sum = 0.f;
        float e[VV];
        #pragma unroll
        for (int j = 0; j < VV; ++j) { e[j] = expf(S[i * VV + j] - m); sum += e[j]; }
        float inv = 1.0f / sum;
        #pragma unroll
        for (int j = 0; j < VV; ++j) S[i * VV + j] = e[j] * inv;
    }
    __syncthreads();
    for (int idx = t; idx < 32 * VV; idx += 256) {
        int c = idx / VV, i = idx - (idx / VV) * VV;
        float sv = 0.f, sve = 0.f;
        #pragma unroll
        for (int j = 0; j < VV; ++j) {
            float p = S[i * VV + j];
            sv  += p * vs[c][j];
            sve += p * rs[c][i - j + 24];
        }
        size_t o = (size_t)(gidx * 32 + c) * 2;
        so[((size_t)n * OO + o) * VV + i]     = sv;
        so[((size_t)n * OO + o + 1) * VV + i] = sve;
        scratch[(2 * c) * VV + i]     = sv;
        scratch[(2 * c + 1) * VV + i] = sve;
    }
    __syncthreads();
    if (t < 64) {
        float s = 0.f, s2 = 0.f;
        #pragma unroll
        for (int k = 0; k < VV; ++k) { float w0 = scratch[t * VV + k]; s += w0; s2 += w0 * w0; }
        int ch = gidx * 64 + t;
        atomicAdd(&ostat[2 * ch], s);
        atomicAdd(&ostat[2 * ch + 1], s2);
    }
}

// ---------------- kernel 5: out = x * (1 + sigmoid(bn(so[2p]) + bn(so[2p+1]))) ----------------
__global__ __launch_bounds__(256) void k_final(const float* __restrict__ x,
                                               const float* __restrict__ so,
                                               const float* __restrict__ ostat,
                                               const float* __restrict__ go,
                                               const float* __restrict__ bo,
                                               float* __restrict__ out) {
    int b = blockIdx.x;            // n*CC + p
    int n = b >> 8, p = b & 255;
    int t = threadIdx.x;
    __shared__ float osl[2], oshl[2], orow[VV];
    if (t < 2) {
        int ch = 2 * p + t;
        float s = ostat[2 * ch], s2 = ostat[2 * ch + 1];
        float m = s * (1.0f / NV), var = s2 * (1.0f / NV) - m * m;
        float sc = go[ch] * rsqrtf(var + 1e-5f);
        osl[t] = sc; oshl[t] = bo[ch] - m * sc;
    }
    __syncthreads();
    if (t < VV) {
        int o0 = 2 * p, o1 = 2 * p + 1;
        float a  = so[((size_t)n * OO + o0) * VV + t] * osl[0] + oshl[0];
        float c2 = so[((size_t)n * OO + o1) * VV + t] * osl[1] + oshl[1];
        float z = a + c2;
        orow[t] = 1.0f + 1.0f / (1.0f + expf(-z));
    }
    __syncthreads();
    const float4* x4 = (const float4*)(x + (size_t)b * (TT * VV));
    float4* y4 = (float4*)(out + (size_t)b * (TT * VV));
    for (int wv = t; wv < (TT * VV) / 4; wv += 256) {
        float4 xv = x4[wv];
        int e = 4 * wv;
        int v0 = e % VV;
        float4 r;
        int v;
        v = v0;                      r.x = xv.x * orow[v];
        v = v0 + 1; if (v >= VV) v -= VV; r.y = xv.y * orow[v];
        v = v0 + 2; if (v >= VV) v -= VV; r.z = xv.z * orow[v];
        v = v0 + 3; if (v >= VV) v -= VV; r.w = xv.w * orow[v];
        y4[wv] = r;
    }
}

extern "C" void kernel_launch(void* const* d_in, const int* in_sizes, int n_in,
                              void* d_out, int out_size, void* d_ws, size_t ws_size,
                              hipStream_t stream) {
    (void)in_sizes; (void)n_in; (void)out_size; (void)ws_size;
    const float* x        = (const float*)d_in[0];
    const float* w_qkv    = (const float*)d_in[1];
    const float* relative = (const float*)d_in[2];
    const float* bn_qkv_g = (const float*)d_in[3];
    const float* bn_qkv_b = (const float*)d_in[4];
    const float* bn_sim_g = (const float*)d_in[5];
    const float* bn_sim_b = (const float*)d_in[6];
    const float* bn_out_g = (const float*)d_in[7];
    const float* bn_out_b = (const float*)d_in[8];
    float* out = (float*)d_out;

    float* ws = (float*)d_ws;
    float* w_y    = ws;                 // NN*CC*VV      = 409600
    float* w_qkvp = ws + 409600;        // NN*OO*VV      = 819200
    float* w_stk  = ws + 1228800;       // NN*24*STK     = 960000
    float* w_so   = ws + 2188800;       // NN*OO*VV      = 819200
    float* qstat  = ws + 3008000;       // 1024 (sum,sumsq per 512 ch)
    float* sstat  = qstat + 1024;       // 48
    float* ostat  = sstat + 48;         // 1024
    // zero all stat accumulators in one capturable memset (2096 floats)
    hipMemsetAsync(qstat, 0, 2096 * sizeof(float), stream);

    k_mean<<<NN * CC, 256, 0, stream>>>(x, w_y);
    k_gemm<<<NN * 8, 256, 0, stream>>>(w_y, w_qkv, w_qkvp, qstat);
    k_scores<<<NN * GG, 256, 0, stream>>>(w_qkvp, relative, qstat, bn_qkv_g, bn_qkv_b, w_stk, sstat);
    k_attnout<<<NN * GG, 256, 0, stream>>>(w_stk, w_qkvp, relative, qstat, bn_qkv_g, bn_qkv_b,
                                           sstat, bn_sim_g, bn_sim_b, w_so, ostat);
    k_final<<<NN * CC, 256, 0, stream>>>(x, w_so, ostat, bn_out_g, bn_out_b, out);
}